// Round 3
// baseline (489.620 us; speedup 1.0000x reference)
//
#include <hip/hip_runtime.h>
#include <hip/hip_fp16.h>

#define BB 512
#define TT 2048

typedef _Float16 half2v __attribute__((ext_vector_type(2)));

// ---------- fast math helpers ----------
__device__ __forceinline__ float fexp2(float x){ return __builtin_amdgcn_exp2f(x); }
__device__ __forceinline__ float frcp(float x){ return __builtin_amdgcn_rcpf(x); }
__device__ __forceinline__ float sigm(float x){ return frcp(1.f + fexp2(-1.4426950408889634f*x)); }
__device__ __forceinline__ float tanhfast(float x){ return 1.f - 2.f*frcp(1.f + fexp2(2.8853900817779268f*x)); }

#define QB(v, ctrl) __int_as_float(__builtin_amdgcn_mov_dpp(__float_as_int(v), (ctrl), 0xF, 0xF, true))

__device__ __forceinline__ float dot2h(unsigned a, unsigned b, float c){
#if __has_builtin(__builtin_amdgcn_fdot2)
  return __builtin_amdgcn_fdot2(__builtin_bit_cast(half2v, a),
                                __builtin_bit_cast(half2v, b), c, false);
#else
  half2v av = __builtin_bit_cast(half2v, a);
  half2v bv = __builtin_bit_cast(half2v, b);
  float r = fmaf((float)av.x, (float)bv.x, c);
  return fmaf((float)av.y, (float)bv.y, r);
#endif
}

// ---------- pass 1: xg[b][tg][e][u] = f16( -k_q * (x·W_ih^T + b_ih + b_hh) ) ----------
__global__ __launch_bounds__(256) void k_xg2(const float* __restrict__ x,
                                             const float* __restrict__ Wih,
                                             const float* __restrict__ bih,
                                             const float* __restrict__ bhh,
                                             unsigned* __restrict__ xg_u)
{
  __shared__ float    xs[13*256];
  __shared__ unsigned ot[32*212];
  const int tid = threadIdx.x;
  const int b   = blockIdx.x >> 3;
  const int t0  = (blockIdx.x & 7) << 8;

  const float* xsrc = x + ((size_t)b*TT + t0)*13;
  #pragma unroll
  for (int it=0; it<13; ++it) xs[tid + it*256] = xsrc[tid + it*256];
  __syncthreads();

  float xv[13];
  #pragma unroll
  for (int k=0;k<13;k++) xv[k] = xs[tid*13+k];

  const int tgl = tid >> 3, u = tid & 7;
  unsigned short* otp = (unsigned short*)ot;
  #pragma unroll 2
  for (int g=0; g<52; ++g){            // g = q*13+j; q==2 <=> 26<=g<39
    float acc = bih[g] + bhh[g];
    #pragma unroll
    for (int k=0;k<13;k++) acc = fmaf(Wih[g*13+k], xv[k], acc);
    const float sc = (g>=26 && g<39) ? -2.8853900817779268f : -1.4426950408889634f;
    otp[tgl*424 + g*8 + u] = __half_as_ushort(__float2half(acc*sc));
  }
  __syncthreads();

  unsigned* dst = xg_u + ((((size_t)b*256 + (t0>>3))*416) >> 1);
  #pragma unroll
  for (int it=0; it<26; ++it){
    int i2  = tid + it*256;
    int us  = i2*2;
    int t2  = (int)((unsigned)us / 416u);
    int rem = us - t2*416;
    dst[i2] = ot[t2*212 + (rem>>1)];
  }
}

// ---------- pass 2: recurrence. 1 chain/wave; lane 4j+q owns gate q of unit j ----------
__global__ __launch_bounds__(64) void k_rec3(const float* __restrict__ Whh,
                                             const unsigned short* __restrict__ xg,
                                             unsigned short* __restrict__ hs)
{
  const int lane = threadIdx.x;
  const int b    = blockIdx.x;
  const int q    = lane & 3;
  const int j    = lane >> 2;             // 0..15 (13..15 padding)
  const int jc   = (j < 13) ? j : 12;
  const int e    = q*13 + jc;

  const float kq = (q==2) ? -2.8853900817779268f : -1.4426950408889634f;
  const float gm = (q==2) ? -5.7707801635558536f : 1.f;
  const float ga = (q==2) ?  2.8853900817779268f : 0.f;

  // W_hh row, pre-scaled by -k_q, packed f16 pairs
  float wt[14];
  #pragma unroll
  for (int k=0;k<13;k++) wt[k] = Whh[e*13 + k]*kq;
  wt[13] = 0.f;
  unsigned wp[7];
  #pragma unroll
  for (int m=0;m<7;m++)
    wp[m] = (unsigned)__half_as_ushort(__float2half(wt[2*m]))
          | ((unsigned)__half_as_ushort(__float2half(wt[2*m+1])) << 16);

  const char* gbase = (const char*)xg + ((size_t)b*256*416 + (size_t)e*8)*2;
  uint4 A  = *(const uint4*)(gbase);
  uint4 Bv = *(const uint4*)(gbase + 832);
  uint4 C  = *(const uint4*)(gbase + 2*832);

  float h = 0.f, c_ = 0.f;                // c_ carries -2.885*c
  unsigned hp[7];
  #pragma unroll
  for (int m=0;m<7;m++) hp[m] = 0u;

  const bool wr = (q==0) && (j<13);
  uint4* hsrow = (uint4*)(hs + ((size_t)b*13 + jc)*TT);
  unsigned pkprev = 0u, pk0=0u, pk1=0u, pk2=0u, pk3=0u;

#define STEP(w, hi, u) do {                                                   \
    half2v xh = __builtin_bit_cast(half2v, (w));                              \
    float xv  = (hi) ? (float)xh.y : (float)xh.x;                             \
    float dA = dot2h(wp[0], hp[0], xv);                                       \
    dA = dot2h(wp[1], hp[1], dA);                                             \
    dA = dot2h(wp[2], hp[2], dA);                                             \
    dA = dot2h(wp[3], hp[3], dA);                                             \
    float dB = dot2h(wp[4], hp[4], 0.f);                                      \
    dB = dot2h(wp[5], hp[5], dB);                                             \
    dB = dot2h(wp[6], hp[6], dB);                                             \
    float s  = dA + dB;                                                       \
    float r  = frcp(1.f + fexp2(s));                                          \
    float g  = fmaf(gm, r, ga);                                               \
    float ggb = QB(g, 0xAA);                                                  \
    float gfb = QB(g, 0x55);                                                  \
    float gob = QB(g, 0xFF);                                                  \
    float t1 = g * ggb;                                                       \
    c_ = fmaf(gfb, c_, t1);                                                   \
    float tc = fmaf(2.f, frcp(1.f + fexp2(c_)), -1.f);                        \
    h = gob * tc;                                                             \
    unsigned hu = (unsigned)__half_as_ushort(__float2half(h));                \
    if ((u) & 1) { unsigned pp = pkprev | (hu << 16);                         \
      if ((u)==1) pk0=pp; else if ((u)==3) pk1=pp;                            \
      else if ((u)==5) pk2=pp; else pk3=pp; }                                 \
    else pkprev = hu;                                                         \
    int hv_ = (int)hu;                                                        \
    int r0  = __builtin_amdgcn_readlane(hv_, 0);                              \
    int r1  = __builtin_amdgcn_readlane(hv_, 4);                              \
    int r2  = __builtin_amdgcn_readlane(hv_, 8);                              \
    int r3  = __builtin_amdgcn_readlane(hv_, 12);                             \
    int r4  = __builtin_amdgcn_readlane(hv_, 16);                             \
    int r5  = __builtin_amdgcn_readlane(hv_, 20);                             \
    int r6  = __builtin_amdgcn_readlane(hv_, 24);                             \
    int r7  = __builtin_amdgcn_readlane(hv_, 28);                             \
    int r8  = __builtin_amdgcn_readlane(hv_, 32);                             \
    int r9  = __builtin_amdgcn_readlane(hv_, 36);                             \
    int r10 = __builtin_amdgcn_readlane(hv_, 40);                             \
    int r11 = __builtin_amdgcn_readlane(hv_, 44);                             \
    int r12 = __builtin_amdgcn_readlane(hv_, 48);                             \
    hp[0] = (unsigned)(r0  | (r1  << 16));                                    \
    hp[1] = (unsigned)(r2  | (r3  << 16));                                    \
    hp[2] = (unsigned)(r4  | (r5  << 16));                                    \
    hp[3] = (unsigned)(r6  | (r7  << 16));                                    \
    hp[4] = (unsigned)(r8  | (r9  << 16));                                    \
    hp[5] = (unsigned)(r10 | (r11 << 16));                                    \
    hp[6] = (unsigned)(r12);                                                  \
  } while(0)

  for (int tg=0; tg<256; ++tg){
    const int pf = (tg+3 < 256) ? tg+3 : 255;
    uint4 nb = *(const uint4*)(gbase + (size_t)pf*832);

    STEP(A.x, 0, 0); STEP(A.x, 1, 1);
    STEP(A.y, 0, 2); STEP(A.y, 1, 3);
    STEP(A.z, 0, 4); STEP(A.z, 1, 5);
    STEP(A.w, 0, 6); STEP(A.w, 1, 7);

    if (wr) hsrow[tg] = make_uint4(pk0, pk1, pk2, pk3);

    A = Bv; Bv = C; C = nb;
  }
#undef STEP
}

// ---------- pass 3: out[b][t] = sigmoid( fc_b + sum_j fc_w[j]*hs[b][j][t] ) ----------
__global__ __launch_bounds__(256) void k_out2(const unsigned short* __restrict__ hs,
                                              const float* __restrict__ fcw,
                                              const float* __restrict__ fcb,
                                              float* __restrict__ out)
{
  int idx = blockIdx.x*256 + threadIdx.x;   // over B*T
  int b   = idx >> 11;
  int t   = idx & 2047;
  const unsigned short* row = hs + (size_t)b*13*TT + t;
  float acc = fcb[0];
  #pragma unroll
  for (int j=0;j<13;j++){
    float hj = (float)__builtin_bit_cast(_Float16, row[(size_t)j*TT]);
    acc = fmaf(fcw[j], hj, acc);
  }
  out[idx] = sigm(acc);
}

// ---------- fallback (no workspace) ----------
__global__ __launch_bounds__(64) void k_rec_fb(
    const float* __restrict__ x,   const float* __restrict__ Whh,
    const float* __restrict__ Wih, const float* __restrict__ bih, const float* __restrict__ bhh,
    const float* __restrict__ fcw, const float* __restrict__ fcb,
    float* __restrict__ out)
{
  const int lane = threadIdx.x;
  const int c    = lane >> 4;
  const int j    = lane & 15;
  const int b    = blockIdx.x*4 + c;
  const bool act = (j < 13);
  const int jj   = act ? j : 0;

  float whh[4][13], wih[4][13], bias[4];
  #pragma unroll
  for (int q=0;q<4;q++){
    #pragma unroll
    for (int k=0;k<13;k++){
      float w1 = Whh[(q*13+jj)*13 + k];
      float w2 = Wih[(q*13+jj)*13 + k];
      whh[q][k] = act ? w1 : 0.f;
      wih[q][k] = act ? w2 : 0.f;
    }
    bias[q] = bih[q*13+jj] + bhh[q*13+jj];
  }
  const float fcwj = act ? fcw[jj] : 0.f;
  const float fcb0 = fcb[0];

  const float* xpf = x + (size_t)b*(TT*13) + jj;
  float* op = out + (size_t)b*TT;

  float h = 0.f, cs = 0.f;
  float xsc = *xpf;

  for (int t=0; t<TT; ++t){
    float xscn = 0.f;
    if (t+1 < TT) { xpf += 13; xscn = *xpf; }

    float hb[13], xb[13];
    {
      int hbits = __float_as_int(h);
      int xbits = __float_as_int(xsc);
      #define HB(k) hb[k] = __int_as_float(__builtin_amdgcn_ds_swizzle(hbits, ((k)<<5)|0x10)); \
                    xb[k] = __int_as_float(__builtin_amdgcn_ds_swizzle(xbits, ((k)<<5)|0x10));
      HB(0) HB(1) HB(2) HB(3) HB(4) HB(5) HB(6) HB(7) HB(8) HB(9) HB(10) HB(11) HB(12)
      #undef HB
    }
    float a0 = bias[0], a1 = bias[1], a2 = bias[2], a3 = bias[3];
    #pragma unroll
    for (int k=0;k<13;k++){
      float xk = xb[k], hk = hb[k];
      a0 += wih[0][k]*xk + whh[0][k]*hk;
      a1 += wih[1][k]*xk + whh[1][k]*hk;
      a2 += wih[2][k]*xk + whh[2][k]*hk;
      a3 += wih[3][k]*xk + whh[3][k]*hk;
    }
    float ig = sigm(a0), fg = sigm(a1), gg = tanhfast(a2), og = sigm(a3);
    cs = fg*cs + ig*gg;
    h  = og * tanhfast(cs);

    float p = act ? fcwj*h : 0.f;
    #define RED(m) p += __int_as_float(__builtin_amdgcn_ds_swizzle(__float_as_int(p), ((m)<<10)|0x1F));
    RED(1) RED(2) RED(4) RED(8)
    #undef RED
    if (j == 0) op[t] = sigm(p + fcb0);
    xsc = xscn;
  }
}

extern "C" void kernel_launch(void* const* d_in, const int* in_sizes, int n_in,
                              void* d_out, int out_size, void* d_ws, size_t ws_size,
                              hipStream_t stream)
{
  const float* x   = (const float*)d_in[0];
  const float* Wih = (const float*)d_in[1];
  const float* Whh = (const float*)d_in[2];
  const float* bih = (const float*)d_in[3];
  const float* bhh = (const float*)d_in[4];
  const float* fcw = (const float*)d_in[5];
  const float* fcb = (const float*)d_in[6];
  float* out = (float*)d_out;

  const size_t XG_BYTES = (size_t)BB*256*416*2;   // 109,051,904  f16 [b][tg][52][8]
  const size_t HS_BYTES = (size_t)BB*13*TT*2;     //  27,262,976  f16 [b][j][t]

  if (ws_size >= XG_BYTES + HS_BYTES){
    unsigned*       xg = (unsigned*)d_ws;
    unsigned short* hs = (unsigned short*)((char*)d_ws + XG_BYTES);
    k_xg2<<<dim3(BB*8), dim3(256), 0, stream>>>(x, Wih, bih, bhh, xg);
    k_rec3<<<dim3(BB), dim3(64), 0, stream>>>(Whh, (const unsigned short*)xg, hs);
    k_out2<<<dim3((BB*TT)/256), dim3(256), 0, stream>>>(hs, fcw, fcb, out);
  } else {
    k_rec_fb<<<dim3(BB/4), dim3(64), 0, stream>>>(x, Whh, Wih, bih, bhh, fcw, fcb, out);
  }
}

// Round 4
// 339.343 us; speedup vs baseline: 1.4428x; 1.4428x over previous
//
#include <hip/hip_runtime.h>
#include <hip/hip_fp16.h>

#define BB 512
#define TT 2048

typedef _Float16 half2v __attribute__((ext_vector_type(2)));

// ---------- fast math helpers ----------
__device__ __forceinline__ float fexp2(float x){ return __builtin_amdgcn_exp2f(x); }
__device__ __forceinline__ float frcp(float x){ return __builtin_amdgcn_rcpf(x); }
__device__ __forceinline__ float sigm(float x){ return frcp(1.f + fexp2(-1.4426950408889634f*x)); }
__device__ __forceinline__ float tanhfast(float x){ return 1.f - 2.f*frcp(1.f + fexp2(2.8853900817779268f*x)); }

#define QB(v, ctrl) __int_as_float(__builtin_amdgcn_mov_dpp(__float_as_int(v), (ctrl), 0xF, 0xF, true))
#define RL(v, l)    __builtin_amdgcn_readlane((v), (l))

// ---------- pass 1: xg[b][tg][e][u] = f16( -k_q * (x·W_ih^T + b_ih + b_hh) ) ----------
// e = q*13+j, u = t&7;  k_q = 2*log2e for q==2 (tanh gate), log2e otherwise.
__global__ __launch_bounds__(256) void k_xg2(const float* __restrict__ x,
                                             const float* __restrict__ Wih,
                                             const float* __restrict__ bih,
                                             const float* __restrict__ bhh,
                                             unsigned* __restrict__ xg_u)
{
  __shared__ float    xs[13*256];
  __shared__ unsigned ot[32*212];
  const int tid = threadIdx.x;
  const int b   = blockIdx.x >> 3;
  const int t0  = (blockIdx.x & 7) << 8;

  const float* xsrc = x + ((size_t)b*TT + t0)*13;
  #pragma unroll
  for (int it=0; it<13; ++it) xs[tid + it*256] = xsrc[tid + it*256];
  __syncthreads();

  float xv[13];
  #pragma unroll
  for (int k=0;k<13;k++) xv[k] = xs[tid*13+k];

  const int tgl = tid >> 3, u = tid & 7;
  unsigned short* otp = (unsigned short*)ot;
  #pragma unroll 2
  for (int g=0; g<52; ++g){            // g = q*13+j; q==2 <=> 26<=g<39
    float acc = bih[g] + bhh[g];
    #pragma unroll
    for (int k=0;k<13;k++) acc = fmaf(Wih[g*13+k], xv[k], acc);
    const float sc = (g>=26 && g<39) ? -2.8853900817779268f : -1.4426950408889634f;
    otp[tgl*424 + g*8 + u] = __half_as_ushort(__float2half(acc*sc));
  }
  __syncthreads();

  unsigned* dst = xg_u + ((((size_t)b*256 + (t0>>3))*416) >> 1);
  #pragma unroll
  for (int it=0; it<26; ++it){
    int i2  = tid + it*256;
    int us  = i2*2;
    int t2  = (int)((unsigned)us / 416u);
    int rem = us - t2*416;
    dst[i2] = ot[t2*212 + (rem>>1)];
  }
}

// ---------- pass 2: recurrence. 1 chain/wave; lane 4j+q owns gate q of unit j ----------
__global__ __launch_bounds__(64, 1) void k_rec4(const float* __restrict__ Whh,
                                                const unsigned short* __restrict__ xg,
                                                unsigned short* __restrict__ hs)
{
  const int lane = threadIdx.x;
  const int b    = blockIdx.x;
  const int q    = lane & 3;
  const int j    = lane >> 2;             // 0..15 (13..15 padding)
  const int jc   = (j < 13) ? j : 12;
  const int e    = q*13 + jc;

  const float kq = (q==2) ? -2.8853900817779268f : -1.4426950408889634f;
  const float gm = (q==2) ? -5.7707801635558536f : 1.f;
  const float ga = (q==2) ?  2.8853900817779268f : 0.f;

  // W_hh row, pre-scaled by k_q (f32)
  float w[13];
  #pragma unroll
  for (int k=0;k<13;k++) w[k] = Whh[e*13 + k]*kq;

  const char* gbase = (const char*)xg + ((size_t)b*256*416 + (size_t)e*8)*2;

  float h = 0.f, c_ = 0.f;                // c_ carries -2*log2e*c
  float hb0=0,hb1=0,hb2=0,hb3=0,hb4=0,hb5=0,hb6=0,hb7=0,hb8=0,hb9=0,hb10=0,hb11=0,hb12=0;

  const bool wr = (q==0) && (j<13);
  uint4* hsrow = (uint4*)(hs + ((size_t)b*13 + jc)*TT);
  float hprev = 0.f;
  unsigned pk0=0u, pk1=0u, pk2=0u, pk3=0u;

#define STEP(xv_, u_) do {                                                    \
    float dA = fmaf(w[0], hb0, (xv_));                                        \
    dA = fmaf(w[1], hb1, dA);                                                 \
    dA = fmaf(w[2], hb2, dA);                                                 \
    dA = fmaf(w[3], hb3, dA);                                                 \
    dA = fmaf(w[4], hb4, dA);                                                 \
    float dB = w[5]*hb5;                                                      \
    dB = fmaf(w[6], hb6, dB);                                                 \
    dB = fmaf(w[7], hb7, dB);                                                 \
    dB = fmaf(w[8], hb8, dB);                                                 \
    float dC = w[9]*hb9;                                                      \
    dC = fmaf(w[10], hb10, dC);                                               \
    dC = fmaf(w[11], hb11, dC);                                               \
    dC = fmaf(w[12], hb12, dC);                                               \
    float s  = (dB + dC) + dA;                                                \
    float r  = frcp(1.f + fexp2(s));                                          \
    float g  = fmaf(gm, r, ga);                                               \
    float ggb = QB(g, 0xAA);                                                  \
    float gfb = QB(g, 0x55);                                                  \
    float gob = QB(g, 0xFF);                                                  \
    float go2 = gob + gob;                                                    \
    c_ = fmaf(gfb, c_, g*ggb);                                                \
    float r2 = frcp(1.f + fexp2(c_));                                         \
    h = fmaf(go2, r2, -gob);                                                  \
    if ((u_) & 1) {                                                           \
      unsigned pp = __builtin_bit_cast(unsigned,                              \
                      __builtin_amdgcn_cvt_pkrtz(hprev, h));                  \
      if ((u_)==1) pk0=pp; else if ((u_)==3) pk1=pp;                          \
      else if ((u_)==5) pk2=pp; else pk3=pp;                                  \
    } else hprev = h;                                                         \
    int hv_ = __float_as_int(h);                                              \
    hb0  = __int_as_float(RL(hv_, 0));                                        \
    hb1  = __int_as_float(RL(hv_, 4));                                        \
    hb2  = __int_as_float(RL(hv_, 8));                                        \
    hb3  = __int_as_float(RL(hv_, 12));                                       \
    hb4  = __int_as_float(RL(hv_, 16));                                       \
    hb5  = __int_as_float(RL(hv_, 20));                                       \
    hb6  = __int_as_float(RL(hv_, 24));                                       \
    hb7  = __int_as_float(RL(hv_, 28));                                       \
    hb8  = __int_as_float(RL(hv_, 32));                                       \
    hb9  = __int_as_float(RL(hv_, 36));                                       \
    hb10 = __int_as_float(RL(hv_, 40));                                       \
    hb11 = __int_as_float(RL(hv_, 44));                                       \
    hb12 = __int_as_float(RL(hv_, 48));                                       \
  } while(0)

#define XLO(w_) (float)(__builtin_bit_cast(half2v, (w_)).x)
#define XHI(w_) (float)(__builtin_bit_cast(half2v, (w_)).y)

#define STEP8(Q) do {                                                         \
    STEP(XLO(Q.x), 0); STEP(XHI(Q.x), 1);                                     \
    STEP(XLO(Q.y), 2); STEP(XHI(Q.y), 3);                                     \
    STEP(XLO(Q.z), 4); STEP(XHI(Q.z), 5);                                     \
    STEP(XLO(Q.w), 6); STEP(XHI(Q.w), 7);                                     \
    if (wr) *hsrow = make_uint4(pk0, pk1, pk2, pk3);                          \
    ++hsrow;                                                                  \
  } while(0)

  uint4 q0 = *(const uint4*)(gbase);
  uint4 q1 = *(const uint4*)(gbase + 832);
  uint4 q2 = *(const uint4*)(gbase + 2*832);
  uint4 q3 = *(const uint4*)(gbase + 3*832);

  for (int i=0; i<63; ++i){
    const char* pn = gbase + (size_t)(4*i+4)*832;
    uint4 c0 = q0; q0 = *(const uint4*)(pn);
    STEP8(c0);
    uint4 c1 = q1; q1 = *(const uint4*)(pn + 832);
    STEP8(c1);
    uint4 c2 = q2; q2 = *(const uint4*)(pn + 2*832);
    STEP8(c2);
    uint4 c3 = q3; q3 = *(const uint4*)(pn + 3*832);
    STEP8(c3);
  }
  STEP8(q0); STEP8(q1); STEP8(q2); STEP8(q3);

#undef STEP8
#undef STEP
#undef XLO
#undef XHI
}

// ---------- pass 3: out[b][t] = sigmoid( fc_b + sum_j fc_w[j]*hs[b][j][t] ) ----------
__global__ __launch_bounds__(256) void k_out2(const unsigned short* __restrict__ hs,
                                              const float* __restrict__ fcw,
                                              const float* __restrict__ fcb,
                                              float* __restrict__ out)
{
  int idx = blockIdx.x*256 + threadIdx.x;   // over B*T
  int b   = idx >> 11;
  int t   = idx & 2047;
  const unsigned short* row = hs + (size_t)b*13*TT + t;
  float acc = fcb[0];
  #pragma unroll
  for (int j=0;j<13;j++){
    float hj = (float)__builtin_bit_cast(_Float16, row[(size_t)j*TT]);
    acc = fmaf(fcw[j], hj, acc);
  }
  out[idx] = sigm(acc);
}

// ---------- fallback (no workspace) ----------
__global__ __launch_bounds__(64) void k_rec_fb(
    const float* __restrict__ x,   const float* __restrict__ Whh,
    const float* __restrict__ Wih, const float* __restrict__ bih, const float* __restrict__ bhh,
    const float* __restrict__ fcw, const float* __restrict__ fcb,
    float* __restrict__ out)
{
  const int lane = threadIdx.x;
  const int c    = lane >> 4;
  const int j    = lane & 15;
  const int b    = blockIdx.x*4 + c;
  const bool act = (j < 13);
  const int jj   = act ? j : 0;

  float whh[4][13], wih[4][13], bias[4];
  #pragma unroll
  for (int q=0;q<4;q++){
    #pragma unroll
    for (int k=0;k<13;k++){
      float w1 = Whh[(q*13+jj)*13 + k];
      float w2 = Wih[(q*13+jj)*13 + k];
      whh[q][k] = act ? w1 : 0.f;
      wih[q][k] = act ? w2 : 0.f;
    }
    bias[q] = bih[q*13+jj] + bhh[q*13+jj];
  }
  const float fcwj = act ? fcw[jj] : 0.f;
  const float fcb0 = fcb[0];

  const float* xpf = x + (size_t)b*(TT*13) + jj;
  float* op = out + (size_t)b*TT;

  float h = 0.f, cs = 0.f;
  float xsc = *xpf;

  for (int t=0; t<TT; ++t){
    float xscn = 0.f;
    if (t+1 < TT) { xpf += 13; xscn = *xpf; }

    float hb[13], xb[13];
    {
      int hbits = __float_as_int(h);
      int xbits = __float_as_int(xsc);
      #define HB(k) hb[k] = __int_as_float(__builtin_amdgcn_ds_swizzle(hbits, ((k)<<5)|0x10)); \
                    xb[k] = __int_as_float(__builtin_amdgcn_ds_swizzle(xbits, ((k)<<5)|0x10));
      HB(0) HB(1) HB(2) HB(3) HB(4) HB(5) HB(6) HB(7) HB(8) HB(9) HB(10) HB(11) HB(12)
      #undef HB
    }
    float a0 = bias[0], a1 = bias[1], a2 = bias[2], a3 = bias[3];
    #pragma unroll
    for (int k=0;k<13;k++){
      float xk = xb[k], hk = hb[k];
      a0 += wih[0][k]*xk + whh[0][k]*hk;
      a1 += wih[1][k]*xk + whh[1][k]*hk;
      a2 += wih[2][k]*xk + whh[2][k]*hk;
      a3 += wih[3][k]*xk + whh[3][k]*hk;
    }
    float ig = sigm(a0), fg = sigm(a1), gg = tanhfast(a2), og = sigm(a3);
    cs = fg*cs + ig*gg;
    h  = og * tanhfast(cs);

    float p = act ? fcwj*h : 0.f;
    #define RED(m) p += __int_as_float(__builtin_amdgcn_ds_swizzle(__float_as_int(p), ((m)<<10)|0x1F));
    RED(1) RED(2) RED(4) RED(8)
    #undef RED
    if (j == 0) op[t] = sigm(p + fcb0);
    xsc = xscn;
  }
}

extern "C" void kernel_launch(void* const* d_in, const int* in_sizes, int n_in,
                              void* d_out, int out_size, void* d_ws, size_t ws_size,
                              hipStream_t stream)
{
  const float* x   = (const float*)d_in[0];
  const float* Wih = (const float*)d_in[1];
  const float* Whh = (const float*)d_in[2];
  const float* bih = (const float*)d_in[3];
  const float* bhh = (const float*)d_in[4];
  const float* fcw = (const float*)d_in[5];
  const float* fcb = (const float*)d_in[6];
  float* out = (float*)d_out;

  const size_t XG_BYTES = (size_t)BB*256*416*2;   // 109,051,904  f16 [b][tg][52][8]
  const size_t HS_BYTES = (size_t)BB*13*TT*2;     //  27,262,976  f16 [b][j][t]

  if (ws_size >= XG_BYTES + HS_BYTES){
    unsigned*       xg = (unsigned*)d_ws;
    unsigned short* hs = (unsigned short*)((char*)d_ws + XG_BYTES);
    k_xg2<<<dim3(BB*8), dim3(256), 0, stream>>>(x, Wih, bih, bhh, xg);
    k_rec4<<<dim3(BB), dim3(64), 0, stream>>>(Whh, (const unsigned short*)xg, hs);
    k_out2<<<dim3((BB*TT)/256), dim3(256), 0, stream>>>(hs, fcw, fcb, out);
  } else {
    k_rec_fb<<<dim3(BB/4), dim3(64), 0, stream>>>(x, Whh, Wih, bih, bhh, fcw, fcb, out);
  }
}